// Round 1
// baseline (315.764 us; speedup 1.0000x reference)
//
#include <hip/hip_runtime.h>
#include <cstdint>

// MambaBlock: out = (silu(x@in_w[:1024]^T + b0) * silu(x@in_w[1024:]^T + b1)) @ out_w^T + out_b
// M = 4*8192 = 32768, D = K = 1024. dt_w/dt_b/A/Dp are dead inputs.

typedef __bf16 bf16x8 __attribute__((ext_vector_type(8)));
typedef float f32x4 __attribute__((ext_vector_type(4)));

#define M_TOTAL 32768
#define KD 1024

// global -> LDS direct copy, 16B per lane. lds_u must be wave-uniform;
// HW writes lds_u + lane*16. Casts per LLVM addrspacecast semantics:
// generic->AS1 is numeric identity, generic->AS3 is low-32-bit truncation.
__device__ __forceinline__ void gload_lds16(const void* g, void* lds_u) {
  __builtin_amdgcn_global_load_lds(
      (__attribute__((address_space(1))) void*)(uintptr_t)g,
      (__attribute__((address_space(3))) void*)(uint32_t)(uintptr_t)lds_u,
      16, 0, 0);
}

__device__ __forceinline__ float silu_f(float v) {
  return v / (1.0f + __expf(-v));
}

// ---------------- cast fp32 -> bf16, 8 elems/thread ----------------
__global__ void cast_f32_to_bf16_x8(const float* __restrict__ in,
                                    __bf16* __restrict__ out, int n8) {
  int i = blockIdx.x * blockDim.x + threadIdx.x;
  if (i >= n8) return;
  const float4* p = (const float4*)in;
  float4 v0 = p[2 * i];
  float4 v1 = p[2 * i + 1];
  bf16x8 o;
  o[0] = (__bf16)v0.x; o[1] = (__bf16)v0.y; o[2] = (__bf16)v0.z; o[3] = (__bf16)v0.w;
  o[4] = (__bf16)v1.x; o[5] = (__bf16)v1.y; o[6] = (__bf16)v1.z; o[7] = (__bf16)v1.w;
  ((bf16x8*)out)[i] = o;
}

// ---------------- GEMM1 fused: gated = silu(X@W1a^T+b)*silu(X@W1b^T+b2) ----
// X: [M][1024] bf16, W1: [2048][1024] bf16, G: [M][1024] bf16.
// 128x128 tile over (m, d), dual-B (rows n and n+1024 of W1), BK=32,
// 256 threads = 4 waves in 2x2, each wave 64x64 via 4x4 16x16x32 MFMA.
__global__ __launch_bounds__(256, 2)
void gemm1_silu(const __bf16* __restrict__ X, const __bf16* __restrict__ W1,
                const float* __restrict__ in_b, __bf16* __restrict__ G) {
  __shared__ __bf16 lA[128 * 32];
  __shared__ __bf16 lB1[128 * 32];
  __shared__ __bf16 lB2[128 * 32];

  const int t = threadIdx.x;
  const int w = t >> 6;
  const int lane = t & 63;
  const int wr = w >> 1, wc = w & 1;
  const int lr = lane & 15;   // row (A) / col (B) within 16
  const int lk = lane >> 4;   // k-block 0..3 -> k = lk*8 + i

  const long m0 = (long)blockIdx.y * 128;
  const int n0 = blockIdx.x * 128;

  // staging: thread t loads 16B; row = t>>2 (0..63), 16B-block = t&3
  const int srow = t >> 2;
  const int sblk = t & 3;
  const __bf16* gA = X + (m0 + srow) * KD + sblk * 8;
  const __bf16* gB1 = W1 + (size_t)(n0 + srow) * KD + sblk * 8;
  const __bf16* gB2 = W1 + (size_t)(n0 + 1024 + srow) * KD + sblk * 8;
  __bf16* lAw = lA + w * 512;    // wave-uniform LDS bases (1024B per wave)
  __bf16* lB1w = lB1 + w * 512;
  __bf16* lB2w = lB2 + w * 512;

  f32x4 accX[4][4] = {};
  f32x4 accR[4][4] = {};

  for (int k0 = 0; k0 < KD; k0 += 32) {
    gload_lds16(gA, lAw);
    gload_lds16(gA + 64 * KD, lAw + 2048);
    gload_lds16(gB1, lB1w);
    gload_lds16(gB1 + 64 * KD, lB1w + 2048);
    gload_lds16(gB2, lB2w);
    gload_lds16(gB2 + 64 * KD, lB2w + 2048);
    gA += 32; gB1 += 32; gB2 += 32;
    __syncthreads();  // drains vmcnt(0) -> LDS tiles complete

    bf16x8 a[4], b1[4], b2[4];
#pragma unroll
    for (int i = 0; i < 4; ++i)
      a[i] = *(const bf16x8*)(lA + (wr * 64 + i * 16 + lr) * 32 + lk * 8);
#pragma unroll
    for (int j = 0; j < 4; ++j) {
      b1[j] = *(const bf16x8*)(lB1 + (wc * 64 + j * 16 + lr) * 32 + lk * 8);
      b2[j] = *(const bf16x8*)(lB2 + (wc * 64 + j * 16 + lr) * 32 + lk * 8);
    }
#pragma unroll
    for (int i = 0; i < 4; ++i)
#pragma unroll
      for (int j = 0; j < 4; ++j) {
        accX[i][j] = __builtin_amdgcn_mfma_f32_16x16x32_bf16(a[i], b1[j], accX[i][j], 0, 0, 0);
        accR[i][j] = __builtin_amdgcn_mfma_f32_16x16x32_bf16(a[i], b2[j], accR[i][j], 0, 0, 0);
      }
    __syncthreads();  // protect LDS before next-step overwrite
  }

  // epilogue: C/D layout col=lane&15, row=(lane>>4)*4+reg  [m89-verified]
#pragma unroll
  for (int i = 0; i < 4; ++i)
#pragma unroll
    for (int j = 0; j < 4; ++j)
#pragma unroll
      for (int q = 0; q < 4; ++q) {
        const int r = wr * 64 + i * 16 + (lane >> 4) * 4 + q;
        const int c = wc * 64 + j * 16 + (lane & 15);
        const long row = m0 + r;
        const int col = n0 + c;
        float xv = accX[i][j][q] + in_b[col];
        float rs = accR[i][j][q] + in_b[col + 1024];
        G[row * KD + col] = (__bf16)(silu_f(xv) * silu_f(rs));
      }
}

// ---------------- GEMM2: OUT = G @ W2^T + out_b (fp32 out) ----------------
__global__ __launch_bounds__(256, 2)
void gemm2_bias(const __bf16* __restrict__ G, const __bf16* __restrict__ W2,
                const float* __restrict__ out_b, float* __restrict__ OUT) {
  __shared__ __bf16 lA[128 * 32];
  __shared__ __bf16 lB[128 * 32];

  const int t = threadIdx.x;
  const int w = t >> 6;
  const int lane = t & 63;
  const int wr = w >> 1, wc = w & 1;
  const int lr = lane & 15;
  const int lk = lane >> 4;

  const long m0 = (long)blockIdx.y * 128;
  const int n0 = blockIdx.x * 128;

  const int srow = t >> 2;
  const int sblk = t & 3;
  const __bf16* gA = G + (m0 + srow) * KD + sblk * 8;
  const __bf16* gB = W2 + (size_t)(n0 + srow) * KD + sblk * 8;
  __bf16* lAw = lA + w * 512;
  __bf16* lBw = lB + w * 512;

  f32x4 acc[4][4] = {};

  for (int k0 = 0; k0 < KD; k0 += 32) {
    gload_lds16(gA, lAw);
    gload_lds16(gA + 64 * KD, lAw + 2048);
    gload_lds16(gB, lBw);
    gload_lds16(gB + 64 * KD, lBw + 2048);
    gA += 32; gB += 32;
    __syncthreads();

    bf16x8 a[4], b[4];
#pragma unroll
    for (int i = 0; i < 4; ++i)
      a[i] = *(const bf16x8*)(lA + (wr * 64 + i * 16 + lr) * 32 + lk * 8);
#pragma unroll
    for (int j = 0; j < 4; ++j)
      b[j] = *(const bf16x8*)(lB + (wc * 64 + j * 16 + lr) * 32 + lk * 8);
#pragma unroll
    for (int i = 0; i < 4; ++i)
#pragma unroll
      for (int j = 0; j < 4; ++j)
        acc[i][j] = __builtin_amdgcn_mfma_f32_16x16x32_bf16(a[i], b[j], acc[i][j], 0, 0, 0);
    __syncthreads();
  }

#pragma unroll
  for (int i = 0; i < 4; ++i)
#pragma unroll
    for (int j = 0; j < 4; ++j)
#pragma unroll
      for (int q = 0; q < 4; ++q) {
        const int r = wr * 64 + i * 16 + (lane >> 4) * 4 + q;
        const int c = wc * 64 + j * 16 + (lane & 15);
        OUT[(m0 + r) * KD + n0 + c] = acc[i][j][q] + out_b[n0 + c];
      }
}

extern "C" void kernel_launch(void* const* d_in, const int* in_sizes, int n_in,
                              void* d_out, int out_size, void* d_ws, size_t ws_size,
                              hipStream_t stream) {
  const float* x = (const float*)d_in[0];
  const float* in_w = (const float*)d_in[1];
  const float* in_b = (const float*)d_in[2];
  const float* out_w = (const float*)d_in[3];
  const float* out_b = (const float*)d_in[4];
  // d_in[5..8] (dt_w, dt_b, A, Dp) are dead in the reference.

  char* ws = (char*)d_ws;
  __bf16* xb = (__bf16*)(ws);                          // 32768*1024*2 = 67108864 B
  __bf16* w1b = (__bf16*)(ws + (size_t)67108864);      // 2048*1024*2  =  4194304 B
  __bf16* w2b = (__bf16*)(ws + (size_t)71303168);      // 1024*1024*2  =  2097152 B
  __bf16* gb = (__bf16*)(ws + (size_t)73400320);       // 32768*1024*2 = 67108864 B
  // total ws use: 140509184 B

  cast_f32_to_bf16_x8<<<dim3(16384), 256, 0, stream>>>(x, xb, 33554432 / 8);
  cast_f32_to_bf16_x8<<<dim3(1024), 256, 0, stream>>>(in_w, w1b, 2097152 / 8);
  cast_f32_to_bf16_x8<<<dim3(512), 256, 0, stream>>>(out_w, w2b, 1048576 / 8);

  gemm1_silu<<<dim3(8, 256), 256, 0, stream>>>(xb, w1b, in_b, gb);
  gemm2_bias<<<dim3(8, 256), 256, 0, stream>>>(gb, w2b, out_b, (float*)d_out);
}

// Round 2
// 291.719 us; speedup vs baseline: 1.0824x; 1.0824x over previous
//
#include <hip/hip_runtime.h>
#include <cstdint>

// MambaBlock: out = (silu(x@in_w[:1024]^T + b0) * silu(x@in_w[1024:]^T + b1)) @ out_w^T + out_b
// M = 32768, D = K = 1024. dt_w/dt_b/A/Dp are dead inputs.
//
// Structure: 256x256 tile, BK=32, 512 threads (8 waves, 2Mx4N), triple-buffered
// LDS (96 KiB) with prefetch depth 2 and counted vmcnt(4) (never 0 in the main
// loop), raw s_barrier (one per K-tile), T2 swizzle via pre-swizzled global
// source + swizzled ds_read (LDS linear for global_load_lds), setprio around
// the MFMA cluster, bijective XCD swizzle on blockIdx.

typedef __bf16 bf16x8 __attribute__((ext_vector_type(8)));
typedef float f32x4 __attribute__((ext_vector_type(4)));

#define KD 1024
#define NT 32            // K-tiles: 1024/32
#define BUF_ELEMS 16384  // (256*32 A + 256*32 B) elems per buffer

__device__ __forceinline__ void gload_lds16(const void* g, void* lds_u) {
  __builtin_amdgcn_global_load_lds(
      (__attribute__((address_space(1))) void*)(uintptr_t)g,
      (__attribute__((address_space(3))) void*)(uint32_t)(uintptr_t)lds_u,
      16, 0, 0);
}

__device__ __forceinline__ float silu_f(float v) {
  return v / (1.0f + __expf(-v));
}

#define WAITB(N) do { \
  asm volatile("s_waitcnt vmcnt(" #N ")" ::: "memory"); \
  asm volatile("s_barrier" ::: "memory"); } while (0)

// ---------------- casts ----------------
__global__ void cast_f32_to_bf16_x8(const float* __restrict__ in,
                                    __bf16* __restrict__ out, int n8) {
  int i = blockIdx.x * blockDim.x + threadIdx.x;
  if (i >= n8) return;
  const float4* p = (const float4*)in;
  float4 v0 = p[2 * i];
  float4 v1 = p[2 * i + 1];
  bf16x8 o;
  o[0] = (__bf16)v0.x; o[1] = (__bf16)v0.y; o[2] = (__bf16)v0.z; o[3] = (__bf16)v0.w;
  o[4] = (__bf16)v1.x; o[5] = (__bf16)v1.y; o[6] = (__bf16)v1.z; o[7] = (__bf16)v1.w;
  ((bf16x8*)out)[i] = o;
}

// W1' row 2c = in_w row c (x_val), row 2c+1 = in_w row 1024+c (res)
__global__ void cast_w1_interleave(const float* __restrict__ in,
                                   __bf16* __restrict__ out) {
  int i = blockIdx.x * blockDim.x + threadIdx.x;  // 2048*128 threads
  int orow = i >> 7;
  int chunk = i & 127;
  int srow = (orow >> 1) + ((orow & 1) << 10);
  const float4* p = (const float4*)(in + ((size_t)srow << 10) + (chunk << 3));
  float4 v0 = p[0], v1 = p[1];
  bf16x8 o;
  o[0] = (__bf16)v0.x; o[1] = (__bf16)v0.y; o[2] = (__bf16)v0.z; o[3] = (__bf16)v0.w;
  o[4] = (__bf16)v1.x; o[5] = (__bf16)v1.y; o[6] = (__bf16)v1.z; o[7] = (__bf16)v1.w;
  *(bf16x8*)(out + ((size_t)orow << 10) + (chunk << 3)) = o;
}

// ---------------- GEMM core ----------------
// Stage one 256x32 K-tile of A and B into buffer BUF. Per thread: 4 gloads.
// Global source chunk pre-swizzled: lane l covers LDS slot (row l>>2, slot l&3)
// which must hold global chunk (l&3)^((l>>3)&3)  [= slot ^ ((row>>1)&3)].
template <int BUF>
__device__ __forceinline__ void stage_tile(const __bf16*& pa, const __bf16*& pb,
                                           __bf16* smw) {
  __bf16* d = smw + BUF * BUF_ELEMS;
  gload_lds16(pa, d);
  gload_lds16(pa + 128 * KD, d + 4096);
  gload_lds16(pb, d + 8192);
  gload_lds16(pb + 128 * KD, d + 12288);
  pa += 32;
  pb += 32;
}

template <int BUF>
__device__ __forceinline__ void compute_tile(const __bf16* sm, int aoff, int boff,
                                             f32x4 (&acc)[8][4]) {
  const __bf16* base = sm + BUF * BUF_ELEMS;
  bf16x8 af[8], bf[4];
#pragma unroll
  for (int i = 0; i < 8; ++i)
    af[i] = *(const bf16x8*)(base + aoff + i * 512);
#pragma unroll
  for (int j = 0; j < 4; ++j)
    bf[j] = *(const bf16x8*)(base + boff + j * 512);
  __builtin_amdgcn_s_setprio(1);
#pragma unroll
  for (int i = 0; i < 8; ++i)
#pragma unroll
    for (int j = 0; j < 4; ++j)
      acc[i][j] = __builtin_amdgcn_mfma_f32_16x16x32_bf16(af[i], bf[j], acc[i][j], 0, 0, 0);
  __builtin_amdgcn_s_setprio(0);
}

// Fills acc for the 256x256 tile at (m0, n0). A:[M][1024], B:[N_rows][1024].
__device__ __forceinline__ void gemm_core(const __bf16* __restrict__ A,
                                          const __bf16* __restrict__ B,
                                          __bf16* sm, long m0, long n0,
                                          f32x4 (&acc)[8][4]) {
  const int t = threadIdx.x;
  const int w = t >> 6;
  const int lane = t & 63;
  const int lr = lane & 15;
  const int lk = lane >> 4;
  const int wr = w >> 2;  // 0..1 (M)
  const int wc = w & 3;   // 0..3 (N)

  // staging source (per thread, swizzled chunk)
  const int l = lane;
  const int stg_row = w * 16 + (l >> 2);
  const int stg_col = ((l & 3) ^ ((l >> 3) & 3)) << 3;
  const __bf16* pa = A + (m0 + stg_row) * KD + stg_col;
  const __bf16* pb = B + (n0 + stg_row) * KD + stg_col;
  __bf16* smw = sm + w * 512;  // wave-uniform LDS base (1024B per wave-instr)

  // fragment read offsets (elements), swizzled slot = lk ^ ((lr>>1)&3)
  const int swz8 = (lk ^ ((lr >> 1) & 3)) << 3;
  const int aoff = (wr * 128 + lr) * 32 + swz8;          // + i*512
  const int boff = 8192 + (wc * 64 + lr) * 32 + swz8;    // + j*512

#pragma unroll
  for (int i = 0; i < 8; ++i)
#pragma unroll
    for (int j = 0; j < 4; ++j)
      acc[i][j] = (f32x4){0.f, 0.f, 0.f, 0.f};

  // prologue: stage tiles 0,1
  stage_tile<0>(pa, pb, smw);
  stage_tile<1>(pa, pb, smw);

  // tiles 0..29: compute buf t%3, stage tile t+2 into buf (t+2)%3
  for (int it = 0; it < 10; ++it) {
    WAITB(4); stage_tile<2>(pa, pb, smw); compute_tile<0>(sm, aoff, boff, acc);
    WAITB(4); stage_tile<0>(pa, pb, smw); compute_tile<1>(sm, aoff, boff, acc);
    WAITB(4); stage_tile<1>(pa, pb, smw); compute_tile<2>(sm, aoff, boff, acc);
  }
  // tail: tiles 30 (buf0), 31 (buf1)
  WAITB(4); compute_tile<0>(sm, aoff, boff, acc);
  WAITB(0); compute_tile<1>(sm, aoff, boff, acc);
}

// ---------------- GEMM1: Y = X @ W1'^T, pair-silu epilogue -> G bf16 ----------
// N_total = 2048 (interleaved); output G cols = 1024.
__global__ __launch_bounds__(512, 2)
void gemm1_silu(const __bf16* __restrict__ X, const __bf16* __restrict__ W1i,
                const float* __restrict__ in_b, __bf16* __restrict__ G) {
  __shared__ __bf16 sm[3 * BUF_ELEMS];
  // XCD-aware bijective swizzle: nwg = 128*8 = 1024, divisible by 8
  const int bid = blockIdx.x;
  const int swz = (bid & 7) * 128 + (bid >> 3);
  const int m_idx = swz >> 3;   // / 8 n-blocks
  const int n_idx = swz & 7;
  const long m0 = (long)m_idx * 256;
  const long n0 = (long)n_idx * 256;

  f32x4 acc[8][4];
  gemm_core(X, W1i, sm, m0, n0, acc);

  const int lane = threadIdx.x & 63;
  const int w = threadIdx.x >> 6;
  const int wr = w >> 2, wc = w & 3;

  float bj[4];
#pragma unroll
  for (int j = 0; j < 4; ++j) {
    int nn = (int)n0 + wc * 64 + j * 16 + (lane & 15);
    bj[j] = (nn & 1) ? in_b[1024 + (nn >> 1)] : in_b[nn >> 1];
  }
#pragma unroll
  for (int i = 0; i < 8; ++i)
#pragma unroll
    for (int j = 0; j < 4; ++j)
#pragma unroll
      for (int q = 0; q < 4; ++q) {
        int r = wr * 128 + i * 16 + (lane >> 4) * 4 + q;
        float v = acc[i][j][q] + bj[j];
        float s = silu_f(v);
        float p = __shfl_xor(s, 1);
        float g = s * p;
        if (!(lane & 1)) {
          int nn = (int)n0 + wc * 64 + j * 16 + (lane & 15);
          G[(m0 + r) * 1024 + (nn >> 1)] = (__bf16)g;
        }
      }
}

// ---------------- GEMM2: OUT = G @ W2^T + out_b (fp32) ----------------
__global__ __launch_bounds__(512, 2)
void gemm2_bias(const __bf16* __restrict__ G, const __bf16* __restrict__ W2,
                const float* __restrict__ out_b, float* __restrict__ OUT) {
  __shared__ __bf16 sm[3 * BUF_ELEMS];
  // nwg = 128*4 = 512, divisible by 8
  const int bid = blockIdx.x;
  const int swz = (bid & 7) * 64 + (bid >> 3);
  const int m_idx = swz >> 2;   // / 4 n-blocks
  const int n_idx = swz & 3;
  const long m0 = (long)m_idx * 256;
  const long n0 = (long)n_idx * 256;

  f32x4 acc[8][4];
  gemm_core(G, W2, sm, m0, n0, acc);

  const int lane = threadIdx.x & 63;
  const int w = threadIdx.x >> 6;
  const int wr = w >> 2, wc = w & 3;

  float ob[4];
#pragma unroll
  for (int j = 0; j < 4; ++j)
    ob[j] = out_b[(int)n0 + wc * 64 + j * 16 + (lane & 15)];
#pragma unroll
  for (int i = 0; i < 8; ++i)
#pragma unroll
    for (int j = 0; j < 4; ++j)
#pragma unroll
      for (int q = 0; q < 4; ++q) {
        int r = wr * 128 + i * 16 + (lane >> 4) * 4 + q;
        int c = wc * 64 + j * 16 + (lane & 15);
        OUT[(m0 + r) * 1024 + n0 + c] = acc[i][j][q] + ob[j];
      }
}

extern "C" void kernel_launch(void* const* d_in, const int* in_sizes, int n_in,
                              void* d_out, int out_size, void* d_ws, size_t ws_size,
                              hipStream_t stream) {
  const float* x = (const float*)d_in[0];
  const float* in_w = (const float*)d_in[1];
  const float* in_b = (const float*)d_in[2];
  const float* out_w = (const float*)d_in[3];
  const float* out_b = (const float*)d_in[4];
  // d_in[5..8] (dt_w, dt_b, A, Dp) are dead in the reference.

  char* ws = (char*)d_ws;
  __bf16* xb = (__bf16*)(ws);                       // 67108864 B
  __bf16* w1b = (__bf16*)(ws + (size_t)67108864);   //  4194304 B (interleaved)
  __bf16* w2b = (__bf16*)(ws + (size_t)71303168);   //  2097152 B
  __bf16* gb = (__bf16*)(ws + (size_t)73400320);    // 67108864 B

  cast_f32_to_bf16_x8<<<dim3(16384), 256, 0, stream>>>(x, xb, 33554432 / 8);
  cast_w1_interleave<<<dim3(1024), 256, 0, stream>>>(in_w, w1b);
  cast_f32_to_bf16_x8<<<dim3(512), 256, 0, stream>>>(out_w, w2b, 1048576 / 8);

  gemm1_silu<<<dim3(1024), 512, 0, stream>>>(xb, w1b, in_b, gb);
  gemm2_bias<<<dim3(512), 512, 0, stream>>>(gb, w2b, out_b, (float*)d_out);
}